// Round 14
// baseline (1196.590 us; speedup 1.0000x reference)
//
#include <hip/hip_runtime.h>
#include <math.h>

#define B_ 8
#define T_ 512
#define FEAT_ 128
#define TP 256          // T' after frontend
#define DM 128          // d_model
#define DI 256          // d_inner
#define DS 16           // d_state
#define DTR 8
#define NL 10

typedef _Float16 h2 __attribute__((ext_vector_type(2)));
typedef unsigned int uint32;

__device__ __forceinline__ float fsilu(float x){ return x / (1.f + __expf(-x)); }
__device__ __forceinline__ float fsoftplus(float x){ return (x > 20.f) ? x : log1pf(__expf(x)); }

__device__ __forceinline__ uint32 pack_h2(float a, float b){
  union { h2 h; uint32 u; } cv;
  cv.h[0] = (_Float16)a; cv.h[1] = (_Float16)b;   // RNE
  return cv.u;
}
__device__ __forceinline__ h2 as_h2(uint32 u){
  union { uint32 u; h2 h; } cv; cv.u = u; return cv.h;
}

// DPP row_ror move (16-lane row rotate), pure VALU — no LDS pipe.
template<int CTRL>
__device__ __forceinline__ float dpp_ror(float x){
  int v = __builtin_amdgcn_update_dpp(0, __float_as_int(x), CTRL, 0xF, 0xF, false);
  return __int_as_float(v);
}
__device__ __forceinline__ float rsum16(float x){
  x += dpp_ror<0x121>(x);
  x += dpp_ror<0x122>(x);
  x += dpp_ror<0x124>(x);
  x += dpp_ror<0x128>(x);
  return x;
}

// ---------- transpose x [8,512,128] -> xT [8,128,512]
__global__ void k_transpose_x(const float* __restrict__ x, float* __restrict__ xT){
  int idx = blockIdx.x*256 + threadIdx.x;
  if(idx >= B_*FEAT_*T_) return;
  int t = idx % T_; int f = (idx/T_) % FEAT_; int b = idx/(T_*FEAT_);
  xT[idx] = x[((size_t)b*T_ + t)*FEAT_ + f];
}

// ---------- conv weight transforms.
__device__ __forceinline__ void wt_one(const float* __restrict__ w, float* __restrict__ o,
                                       int idx, int CO, int CIN){
  int k = idx % 9; int ci = (idx/9) % CIN; int co = idx/(9*CIN);
  o[((size_t)(ci*(CO>>3) + (co>>3)))*72 + (co&7)*9 + k] = w[idx];
}
__device__ __forceinline__ void wt_pack(const float* __restrict__ w, uint32* __restrict__ o,
                                        int idx, int CO, int CIN){
  int CIN2 = CIN >> 1;
  int k = idx % 9; int ci2 = (idx/9) % CIN2; int co = idx/(9*CIN2);
  float f0 = w[((size_t)co*CIN + 2*ci2 + 0)*9 + k];
  float f1 = w[((size_t)co*CIN + 2*ci2 + 1)*9 + k];
  o[((size_t)(ci2*(CO>>3) + (co>>3)))*72 + (co&7)*9 + k] = pack_h2(f0, f1);
}
__global__ void k_wt_all(const float* __restrict__ w1, const float* __restrict__ w2,
                         const float* __restrict__ w4,
                         float* __restrict__ o1, uint32* __restrict__ o2,
                         uint32* __restrict__ o4){
  int idx = blockIdx.x*256 + threadIdx.x;
  if(idx < 288){ wt_one(w1, o1, idx, 32, 1); return; }
  idx -= 288;
  if(idx < 4608){ wt_pack(w2, o2, idx, 32, 32); return; }
  idx -= 4608;
  if(idx < 18432){ wt_pack(w4, o4, idx, 64, 64); return; }
}
__global__ void k_wt3(const float* __restrict__ w3, uint32* __restrict__ o3){
  int idx = blockIdx.x*256 + threadIdx.x;
  if(idx < 9216) wt_pack(w3, o3, idx, 64, 32);
}

// ---------- pack mamba GEMM weights to h2 (K-pairs), all layers.
__global__ void k_pack_w(const float* __restrict__ in_w, const float* __restrict__ out_w,
                         uint32* __restrict__ in_wh, uint32* __restrict__ out_wh){
  int idx = blockIdx.x*256 + threadIdx.x;
  int tot1 = NL*512*64;
  if(idx < tot1){
    const float* w = in_w + (size_t)idx*2;
    in_wh[idx] = pack_h2(w[0], w[1]);
    return;
  }
  idx -= tot1;
  if(idx < NL*128*128){
    const float* w = out_w + (size_t)idx*2;
    out_wh[idx] = pack_h2(w[0], w[1]);
  }
}

// ---------- fp32 direct conv (t4) — conv1 only (CIN=1).
template<int CIN, int CO, int CPW, int CIG, int COG>
__global__ __launch_bounds__(256) void k_conv_t4(const float* __restrict__ in,
     const float* __restrict__ wt, const float* __restrict__ cb,
     const float* __restrict__ bs, const float* __restrict__ bb,
     float* __restrict__ out, int H, int W){
  constexpr int NS = CO/CPW;
  __shared__ __align__(16) float tile[CIG*360];
  int tid = threadIdx.x;
  int lane = tid & 63;
  int wav = __builtin_amdgcn_readfirstlane(tid >> 6);
  int wpr = W >> 4, hpr = H >> 4;
  int idx = blockIdx.x;
  int cog = idx % COG; idx /= COG;
  int tj = idx % wpr; idx /= wpr;
  int ti = idx % hpr; int b = idx / hpr;
  int i0 = ti*16, j0 = tj*16;
  int r = lane & 15, cg = lane >> 4;
  int wslot = cog*4 + wav;
  const float* wbase = wt + (size_t)wslot*72;
  float acc[CPW][4] = {};
  for(int cig = 0; cig < CIN; cig += CIG){
    __syncthreads();
    for(int u = tid; u < CIG*324; u += 256){
      int ci = u / 324; int rem = u - ci*324; int rr = rem / 18; int cc = rem - rr*18;
      int gi = i0 - 1 + rr, gj = j0 - 1 + cc;
      float v = 0.f;
      if(gi >= 0 && gi < H && gj >= 0 && gj < W)
        v = in[((size_t)(b*CIN + cig + ci)*H + gi)*W + gj];
      tile[ci*360 + rr*20 + cc] = v;
    }
    __syncthreads();
    for(int ci = 0; ci < CIG; ci++){
      const float4* wp4 = (const float4*)(wbase + (size_t)(cig+ci)*(NS*72));
      float4 w4q[18];
      #pragma unroll
      for(int q=0;q<18;q++) w4q[q] = wp4[q];
      const float* wf = (const float*)w4q;
      #pragma unroll
      for(int kh=0;kh<3;kh++){
        float4 a = *(const float4*)&tile[ci*360 + (r+kh)*20 + cg*4];
        float4 bv = *(const float4*)&tile[ci*360 + (r+kh)*20 + cg*4 + 4];
        float v[6] = {a.x,a.y,a.z,a.w,bv.x,bv.y};
        #pragma unroll
        for(int co=0;co<CPW;co++){
          #pragma unroll
          for(int kw=0;kw<3;kw++){
            float wv = wf[co*9 + kh*3 + kw];
            #pragma unroll
            for(int u2=0;u2<4;u2++)
              acc[co][u2] = fmaf(wv, v[kw+u2], acc[co][u2]);
          }
        }
      }
    }
  }
  int i = i0 + r;
  #pragma unroll
  for(int co=0; co<CPW; co++){
    int c = cog*(4*CPW) + wav*CPW + co;
    float s = bs[c], bias = cb[c]*s + bb[c];
    float4 o;
    o.x = fsilu(acc[co][0]*s + bias);
    o.y = fsilu(acc[co][1]*s + bias);
    o.z = fsilu(acc[co][2]*s + bias);
    o.w = fsilu(acc[co][3]*s + bias);
    *(float4*)&out[((size_t)(b*CO + c)*H + i)*W + j0 + cg*4] = o;
  }
}

// ---------- f16-dot2 direct conv (t7b): CIG2=8, reg-staged prefetch pipeline.
template<int CIN2, int CO, int CPW, int CIG2, int COG>
__global__ __launch_bounds__(256) void k_conv_t7(const float* __restrict__ in,
     const uint32* __restrict__ wt, const float* __restrict__ cb,
     const float* __restrict__ bs, const float* __restrict__ bb,
     float* __restrict__ out, int H, int W){
  constexpr int NS = CO/CPW;
  constexpr int NSLAB = CIN2/CIG2;
  constexpr int NEL = CIG2*324;
  constexpr int NLD = (NEL + 255)/256;
  __shared__ __align__(16) uint32 tile[CIG2*360];
  int tid = threadIdx.x;
  int lane = tid & 63;
  int wav = __builtin_amdgcn_readfirstlane(tid >> 6);
  int wpr = W >> 4, hpr = H >> 4;
  int idx = blockIdx.x;
  int cog = idx % COG; idx /= COG;
  int tj = idx % wpr; idx /= wpr;
  int ti = idx % hpr; int b = idx / hpr;
  int i0 = ti*16, j0 = tj*16;
  int r = lane & 15, cg = lane >> 4;
  int wslot = cog*4 + wav;
  const uint32* wbase = wt + (size_t)wslot*72;
  float acc[CPW][4] = {};
  float r0[NLD], r1[NLD];

  auto LOAD = [&](int c2g){
    #pragma unroll
    for(int l=0;l<NLD;l++){
      int u = tid + l*256;
      float v0 = 0.f, v1 = 0.f;
      if(u < NEL){
        int ci2 = u/324; int rem = u - ci2*324; int rr = rem/18; int cc = rem - rr*18;
        int gi = i0 - 1 + rr, gj = j0 - 1 + cc;
        if(gi >= 0 && gi < H && gj >= 0 && gj < W){
          const float* p = in + ((size_t)(b*(CIN2*2) + (c2g+ci2)*2)*H + gi)*W + gj;
          v0 = p[0];
          v1 = p[(size_t)H*W];
        }
      }
      r0[l] = v0; r1[l] = v1;
    }
  };
  auto WRITE = [&](){
    #pragma unroll
    for(int l=0;l<NLD;l++){
      int u = tid + l*256;
      if(u < NEL){
        int ci2 = u/324; int rem = u - ci2*324; int rr = rem/18; int cc = rem - rr*18;
        tile[ci2*360 + rr*20 + cc] = pack_h2(r0[l], r1[l]);
      }
    }
  };

  LOAD(0);
  for(int s=0; s<NSLAB; s++){
    __syncthreads();
    WRITE();
    __syncthreads();
    if(s+1 < NSLAB) LOAD((s+1)*CIG2);
    #pragma unroll
    for(int ci2=0; ci2<CIG2; ci2++){
      int sci2 = s*CIG2 + ci2;
      const uint4* wp4 = (const uint4*)(wbase + (size_t)sci2*(NS*72));
      uint4 w4q[18];
      #pragma unroll
      for(int q=0;q<18;q++) w4q[q] = wp4[q];
      const uint32* wf = (const uint32*)w4q;
      h2 v[3][6];
      #pragma unroll
      for(int kh=0;kh<3;kh++){
        const uint32* trow = &tile[ci2*360 + (r+kh)*20 + cg*4];
        uint4 a4 = *(const uint4*)trow;
        v[kh][0]=as_h2(a4.x); v[kh][1]=as_h2(a4.y);
        v[kh][2]=as_h2(a4.z); v[kh][3]=as_h2(a4.w);
        v[kh][4]=as_h2(trow[4]); v[kh][5]=as_h2(trow[5]);
      }
      #pragma unroll
      for(int co=0;co<CPW;co++){
        #pragma unroll
        for(int kh=0;kh<3;kh++){
          #pragma unroll
          for(int kw=0;kw<3;kw++){
            h2 wv = as_h2(wf[co*9 + kh*3 + kw]);
            #pragma unroll
            for(int u2=0;u2<4;u2++)
              acc[co][u2] = __builtin_amdgcn_fdot2(wv, v[kh][kw+u2], acc[co][u2], false);
          }
        }
      }
    }
  }
  int i = i0 + r;
  #pragma unroll
  for(int co=0; co<CPW; co++){
    int c = cog*(4*CPW) + wav*CPW + co;
    float s = bs[c], bias = cb[c]*s + bb[c];
    float4 o;
    o.x = fsilu(acc[co][0]*s + bias);
    o.y = fsilu(acc[co][1]*s + bias);
    o.z = fsilu(acc[co][2]*s + bias);
    o.w = fsilu(acc[co][3]*s + bias);
    *(float4*)&out[((size_t)(b*CO + c)*H + i)*W + j0 + cg*4] = o;
  }
}

// ---------- 2x2 max pool stride 2
__global__ void k_pool2x2(const float* __restrict__ in, float* __restrict__ out,
                          int C, int Hi, int Wi){
  int Ho = Hi>>1, Wo = Wi>>1;
  int total = B_*C*Ho*Wo;
  int idx = blockIdx.x*256 + threadIdx.x;
  if(idx >= total) return;
  int j = idx % Wo; int i = (idx/Wo)%Ho; int c = (idx/(Wo*Ho))%C; int b = idx/(Wo*Ho*C);
  const float* p = in + (((size_t)(b*C+c)*Hi + 2*i)*Wi + 2*j);
  out[idx] = fmaxf(fmaxf(p[0], p[1]), fmaxf(p[Wi], p[Wi+1]));
}

// ---------- fused (2,1)-maxpool + proj GEMM, split-K x8.
__global__ __launch_bounds__(256) void k_proj(const float* __restrict__ R0,
    const float* __restrict__ W, float* __restrict__ pbuf){
  __shared__ __align__(16) float As[16][33];
  __shared__ __align__(16) float Ws[16][68];
  int tid = threadIdx.x;
  int n0 = blockIdx.x*64, m0 = blockIdx.y*32;
  int kc = blockIdx.z;
  int b = m0 >> 8;
  int t_base = m0 & 255;
  int tx = tid&15, ty = tid>>4;
  float acc[2][4] = {};
  for(int k0=0; k0<256; k0+=16){
    int kg0 = kc*256 + k0;
    if(tid < 128){
      int row = tid>>2, cq = (tid&3)*4;
      #pragma unroll
      for(int c2=0;c2<4;c2++){
        int k = kg0 + cq + c2;
        int c = k>>5, hh = k&31;
        const float* p = R0 + (((size_t)(b*64+c)*64 + 2*hh)*256 + t_base + row);
        As[cq+c2][row] = fmaxf(p[0], p[256]);
      }
    } else {
      int u = tid - 128; int n = u>>1, cq = (u&1)*8;
      const float* wp = W + (size_t)(n0+n)*2048 + kg0 + cq;
      float4 v0 = *(const float4*)wp, v1 = *(const float4*)(wp+4);
      Ws[cq+0][n]=v0.x; Ws[cq+1][n]=v0.y; Ws[cq+2][n]=v0.z; Ws[cq+3][n]=v0.w;
      Ws[cq+4][n]=v1.x; Ws[cq+5][n]=v1.y; Ws[cq+6][n]=v1.z; Ws[cq+7][n]=v1.w;
    }
    __syncthreads();
    #pragma unroll
    for(int kk=0;kk<16;kk++){
      float a0 = As[kk][ty*2+0];
      float a1 = As[kk][ty*2+1];
      float4 w4 = *(const float4*)&Ws[kk][tx*4];
      float wv4[4] = {w4.x,w4.y,w4.z,w4.w};
      #pragma unroll
      for(int j=0;j<4;j++){
        acc[0][j] = fmaf(a0, wv4[j], acc[0][j]);
        acc[1][j] = fmaf(a1, wv4[j], acc[1][j]);
      }
    }
    __syncthreads();
  }
  float* pb = pbuf + (size_t)kc*2048*DM;
  #pragma unroll
  for(int iu=0;iu<2;iu++){
    int m = m0 + ty*2 + iu;
    #pragma unroll
    for(int j=0;j<4;j++){
      int n = n0 + tx*4 + j;
      pb[(size_t)m*DM + n] = acc[iu][j];
    }
  }
}

// ---------- reduce 8 split-K partials + bias + LN + SiLU -> hbuf. 1 wave/row.
__global__ void k_lnp(const float* __restrict__ pbuf, const float* __restrict__ bias,
                      const float* __restrict__ g, const float* __restrict__ b,
                      float* __restrict__ out){
  int row = blockIdx.x;
  int t = threadIdx.x; // 64
  float v0 = bias[t], v1 = bias[t+64];
  #pragma unroll
  for(int kc=0;kc<8;kc++){
    const float* p = pbuf + ((size_t)kc*2048 + row)*DM;
    v0 += p[t]; v1 += p[t+64];
  }
  float s = v0 + v1;
  #pragma unroll
  for(int m=32;m>=1;m>>=1) s += __shfl_xor(s, m);
  float mean = s * (1.f/128.f);
  float e0 = v0-mean, e1 = v1-mean;
  float q = e0*e0 + e1*e1;
  #pragma unroll
  for(int m=32;m>=1;m>>=1) q += __shfl_xor(q, m);
  float inv = rsqrtf(q*(1.f/128.f) + 1e-5f);
  float o0 = fsilu(e0*inv*g[t] + b[t]);
  float o1 = fsilu(e1*inv*g[t+64] + b[t+64]);
  float* po = out + (size_t)row*DM;
  po[t] = o0; po[t+64] = o1;
}

// ---------- fused LN + xz GEMM, h2-dot2 (layer 0 only).
__global__ __launch_bounds__(256) void k_lnxz2(const float* __restrict__ hbuf,
    const float* __restrict__ g, const float* __restrict__ bb,
    const uint32* __restrict__ Wh, float* __restrict__ out){
  __shared__ __align__(16) float lns[32][132];
  __shared__ __align__(16) uint32 ah[32][68];
  __shared__ __align__(16) uint32 wsh[8][68];
  int tid = threadIdx.x;
  int n0 = blockIdx.x*64, m0 = blockIdx.y*32;
  for(int u=tid; u<1024; u+=256){
    int row = u>>5, c4 = (u&31)*4;
    float4 v = *(const float4*)(hbuf + (size_t)(m0+row)*DM + c4);
    lns[row][c4] = v.x; lns[row][c4+1] = v.y; lns[row][c4+2] = v.z; lns[row][c4+3] = v.w;
  }
  __syncthreads();
  {
    int lane = tid & 63, wv = tid >> 6;
    for(int rr = wv; rr < 32; rr += 4){
      float v0 = lns[rr][lane], v1 = lns[rr][lane+64];
      float s = v0+v1;
      #pragma unroll
      for(int mm=32;mm>=1;mm>>=1) s += __shfl_xor(s,mm);
      float mean = s*(1.f/128.f);
      float e0 = v0-mean, e1 = v1-mean;
      float q = e0*e0+e1*e1;
      #pragma unroll
      for(int mm=32;mm>=1;mm>>=1) q += __shfl_xor(q,mm);
      float inv = rsqrtf(q*(1.f/128.f)+1e-5f);
      lns[rr][lane]    = e0*inv*g[lane] + bb[lane];
      lns[rr][lane+64] = e1*inv*g[lane+64] + bb[lane+64];
    }
  }
  __syncthreads();
  for(int u=tid; u<32*64; u+=256){
    int row = u>>6, p = u&63;
    ah[row][p] = pack_h2(lns[row][2*p], lns[row][2*p+1]);
  }
  __syncthreads();
  int tx = tid&15, ty = tid>>4;
  float acc[2][4] = {};
  for(int kp0=0; kp0<64; kp0+=8){
    {
      int n = tid>>2, c = (tid&3)*2;
      uint2 v = *(const uint2*)(Wh + (size_t)(n0+n)*64 + kp0 + c);
      wsh[c+0][n] = v.x; wsh[c+1][n] = v.y;
    }
    __syncthreads();
    #pragma unroll
    for(int kp=0;kp<8;kp++){
      h2 a0 = as_h2(ah[ty*2+0][kp0+kp]);
      h2 a1 = as_h2(ah[ty*2+1][kp0+kp]);
      uint4 w4 = *(const uint4*)&wsh[kp][tx*4];
      acc[0][0] = __builtin_amdgcn_fdot2(a0, as_h2(w4.x), acc[0][0], false);
      acc[0][1] = __builtin_amdgcn_fdot2(a0, as_h2(w4.y), acc[0][1], false);
      acc[0][2] = __builtin_amdgcn_fdot2(a0, as_h2(w4.z), acc[0][2], false);
      acc[0][3] = __builtin_amdgcn_fdot2(a0, as_h2(w4.w), acc[0][3], false);
      acc[1][0] = __builtin_amdgcn_fdot2(a1, as_h2(w4.x), acc[1][0], false);
      acc[1][1] = __builtin_amdgcn_fdot2(a1, as_h2(w4.y), acc[1][1], false);
      acc[1][2] = __builtin_amdgcn_fdot2(a1, as_h2(w4.z), acc[1][2], false);
      acc[1][3] = __builtin_amdgcn_fdot2(a1, as_h2(w4.w), acc[1][3], false);
    }
    __syncthreads();
  }
  #pragma unroll
  for(int iu=0;iu<2;iu++){
    int m = m0 + ty*2 + iu;
    float* po = out + (size_t)m*512 + n0 + tx*4;
    #pragma unroll
    for(int j=0;j<4;j++) po[j] = acc[iu][j];
  }
}

// ---------- fused layer transition: hbuf += y@Wout^T; LN; xz = ln@Wxz^T.
// Row-local: 16 rows/block, grid 128. All staging cooperative+coalesced.
__global__ __launch_bounds__(256) void k_blk(const float* __restrict__ y,
    const uint32* __restrict__ Wout, float* __restrict__ hb,
    const float* __restrict__ g, const float* __restrict__ bb,
    const uint32* __restrict__ Wxz, float* __restrict__ xz){
  __shared__ __align__(16) float hrow[16][132];    // h rows
  __shared__ __align__(16) uint32 ypk[128][18];    // packed y (kp-major)
  __shared__ __align__(16) uint32 wstg[4352];      // W staging (both phases)
  __shared__ __align__(16) uint32 ah[16][66];      // packed LN rows
  int tid = threadIdx.x;
  int m0 = blockIdx.x*16;
  int ty = tid>>4, tx = tid&15;    // ty = row (16), tx = col-group
  // load h rows (residual source)
  for(int u=tid; u<512; u+=256){
    int row = u>>5, c4 = (u&31)*4;
    float4 v = *(const float4*)(hb + (size_t)(m0+row)*DM + c4);
    hrow[row][c4]=v.x; hrow[row][c4+1]=v.y; hrow[row][c4+2]=v.z; hrow[row][c4+3]=v.w;
  }
  // pack y rows: ypk[kp][row]
  for(int u=tid; u<1024; u+=256){
    int row = u>>6, kp2 = (u&63)*2;
    float4 v = *(const float4*)(y + (size_t)(m0+row)*DI + 2*kp2);
    ypk[kp2][row]   = pack_h2(v.x, v.y);
    ypk[kp2+1][row] = pack_h2(v.z, v.w);
  }
  // ---- out-proj: 1 row x 8 cols per thread, K=128 pairs in chunks of 8
  float acc[8] = {};
  for(int kp0=0; kp0<128; kp0+=8){
    __syncthreads();     // wstg free (iter0: also makes ypk visible)
    {
      int n = tid>>1, kq = (tid&1)*4;
      uint4 v = *(const uint4*)(Wout + (size_t)n*128 + kp0 + kq);
      wstg[(kq+0)*132+n]=v.x; wstg[(kq+1)*132+n]=v.y;
      wstg[(kq+2)*132+n]=v.z; wstg[(kq+3)*132+n]=v.w;
    }
    __syncthreads();
    #pragma unroll
    for(int kp=0;kp<8;kp++){
      h2 a = as_h2(ypk[kp0+kp][ty]);
      const uint32* wp = &wstg[kp*132 + tx*8];
      uint4 wA = *(const uint4*)wp;
      uint4 wB = *(const uint4*)(wp+4);
      acc[0] = __builtin_amdgcn_fdot2(a, as_h2(wA.x), acc[0], false);
      acc[1] = __builtin_amdgcn_fdot2(a, as_h2(wA.y), acc[1], false);
      acc[2] = __builtin_amdgcn_fdot2(a, as_h2(wA.z), acc[2], false);
      acc[3] = __builtin_amdgcn_fdot2(a, as_h2(wA.w), acc[3], false);
      acc[4] = __builtin_amdgcn_fdot2(a, as_h2(wB.x), acc[4], false);
      acc[5] = __builtin_amdgcn_fdot2(a, as_h2(wB.y), acc[5], false);
      acc[6] = __builtin_amdgcn_fdot2(a, as_h2(wB.z), acc[6], false);
      acc[7] = __builtin_amdgcn_fdot2(a, as_h2(wB.w), acc[7], false);
    }
  }
  // residual + write new h (own cells -> no race)
  float hv[8];
  #pragma unroll
  for(int j=0;j<8;j++){
    hv[j] = hrow[ty][tx*8+j] + acc[j];
    hrow[ty][tx*8+j] = hv[j];
  }
  {
    float* po = hb + (size_t)(m0+ty)*DM + tx*8;
    float4 o0 = {hv[0],hv[1],hv[2],hv[3]};
    float4 o1 = {hv[4],hv[5],hv[6],hv[7]};
    *(float4*)po = o0; *(float4*)(po+4) = o1;
  }
  __syncthreads();
  // ---- LN in place (wave wv handles rows wv, wv+4, wv+8, wv+12)
  {
    int lane = tid & 63, wv = tid >> 6;
    for(int rr = wv; rr < 16; rr += 4){
      float v0 = hrow[rr][lane], v1 = hrow[rr][lane+64];
      float s = v0+v1;
      #pragma unroll
      for(int mm=32;mm>=1;mm>>=1) s += __shfl_xor(s,mm);
      float mean = s*(1.f/128.f);
      float e0 = v0-mean, e1 = v1-mean;
      float q = e0*e0+e1*e1;
      #pragma unroll
      for(int mm=32;mm>=1;mm>>=1) q += __shfl_xor(q,mm);
      float inv = rsqrtf(q*(1.f/128.f)+1e-5f);
      hrow[rr][lane]    = e0*inv*g[lane] + bb[lane];
      hrow[rr][lane+64] = e1*inv*g[lane+64] + bb[lane+64];
    }
  }
  __syncthreads();
  // pack LN rows
  for(int u=tid; u<1024; u+=256){
    int row = u>>6, p = u&63;
    ah[row][p] = pack_h2(hrow[row][2*p], hrow[row][2*p+1]);
  }
  // ---- xz GEMM: 8 n-chunks of 64; whole-K W staged per chunk
  for(int nc=0; nc<8; nc++){
    __syncthreads();    // ah visible (first) / wstg free
    {
      #pragma unroll
      for(int l=0;l<4;l++){
        int u = tid + l*256;
        int n = u>>4, kq = (u&15)*4;
        uint4 v = *(const uint4*)(Wxz + (size_t)(nc*64+n)*64 + kq);
        wstg[(kq+0)*68+n]=v.x; wstg[(kq+1)*68+n]=v.y;
        wstg[(kq+2)*68+n]=v.z; wstg[(kq+3)*68+n]=v.w;
      }
    }
    __syncthreads();
    float a2[4] = {};
    #pragma unroll 8
    for(int kp=0;kp<64;kp++){
      h2 a = as_h2(ah[ty][kp]);
      uint4 w4 = *(const uint4*)&wstg[kp*68 + tx*4];
      a2[0] = __builtin_amdgcn_fdot2(a, as_h2(w4.x), a2[0], false);
      a2[1] = __builtin_amdgcn_fdot2(a, as_h2(w4.y), a2[1], false);
      a2[2] = __builtin_amdgcn_fdot2(a, as_h2(w4.z), a2[2], false);
      a2[3] = __builtin_amdgcn_fdot2(a, as_h2(w4.w), a2[3], false);
    }
    float4 o = {a2[0],a2[1],a2[2],a2[3]};
    *(float4*)(xz + (size_t)(m0+ty)*512 + nc*64 + tx*4) = o;
  }
}

// ---------- fused: causal dwconv(4)+SiLU -> dbc GEMM -> dt GEMM+softplus.
__global__ __launch_bounds__(256) void k_xproj8(const float* __restrict__ xz,
    const float* __restrict__ cw, const float* __restrict__ cb,
    const float* __restrict__ xpw, const float* __restrict__ dtw,
    const float* __restrict__ dtb_, float* __restrict__ xc_g,
    float* __restrict__ dbc_g, float* __restrict__ dt_g){
  __shared__ float xzs[11][64];
  __shared__ float As[64][9];
  __shared__ float Wp[64][41];
  __shared__ float dtin[8][9];
  __shared__ float dtw_s[256][9];
  int tid = threadIdx.x;
  int row0 = blockIdx.x*8; int b = row0 >> 8; int t0 = row0 & 255;
  int rA = tid & 7, cgA = tid >> 3;
  int dlC = tid & 63, rqC = tid >> 6;
  float acc0 = 0.f, acc1 = 0.f;
  for(int ch=0; ch<4; ch++){
    int d0 = ch*64;
    __syncthreads();
    for(int u=tid; u<11*64; u+=256){
      int rr = u>>6, dl = u&63;
      int t = t0 + rr - 3;
      xzs[rr][dl] = (t >= 0) ? xz[((size_t)(b*TP)+t)*512 + d0 + dl] : 0.f;
    }
    for(int u=tid; u<40*64; u+=256){
      int nn = u>>6, dk = u&63;
      Wp[dk][nn] = xpw[(size_t)nn*DI + d0 + dk];
    }
    __syncthreads();
    {
      float cw0 = cw[(d0+dlC)*4+0], cw1 = cw[(d0+dlC)*4+1];
      float cw2 = cw[(d0+dlC)*4+2], cw3 = cw[(d0+dlC)*4+3];
      float cbv = cb[d0+dlC];
      #pragma unroll
      for(int i=0;i<2;i++){
        int rr = rqC*2 + i;
        float a = cbv;
        a = fmaf(cw0, xzs[rr+0][dlC], a);
        a = fmaf(cw1, xzs[rr+1][dlC], a);
        a = fmaf(cw2, xzs[rr+2][dlC], a);
        a = fmaf(cw3, xzs[rr+3][dlC], a);
        float v = fsilu(a);
        As[dlC][rr] = v;
        xc_g[((size_t)row0 + rr)*DI + d0 + dlC] = v;
      }
    }
    __syncthreads();
    for(int dk=0; dk<64; dk++){
      float a = As[dk][rA];
      acc0 = fmaf(a, Wp[dk][cgA], acc0);
      if(cgA < 8) acc1 = fmaf(a, Wp[dk][cgA+32], acc1);
    }
  }
  if(cgA < 8){
    dtin[rA][cgA] = acc0;
    dbc_g[((size_t)row0 + rA)*40 + cgA + 32] = acc1;
  } else {
    dbc_g[((size_t)row0 + rA)*40 + cgA] = acc0;
  }
  for(int u=tid; u<256*8; u+=256) dtw_s[u>>3][u&7] = dtw[u];
  __syncthreads();
  {
    int d = tid;
    float bias = dtb_[d];
    float w8[8];
    #pragma unroll
    for(int k=0;k<8;k++) w8[k] = dtw_s[d][k];
    #pragma unroll
    for(int r2=0;r2<8;r2++){
      float a = bias;
      #pragma unroll
      for(int k=0;k<8;k++) a = fmaf(dtin[r2][k], w8[k], a);
      dt_g[((size_t)row0 + r2)*DI + d] = fsoftplus(a);
    }
  }
}

// ---------- chunked selective scan v4: 8 chunks of 32, block 1024 thr, DPP reduce.
__global__ __launch_bounds__(1024) void k_scan4(const float* __restrict__ dtb,
      const float* __restrict__ xc, const float* __restrict__ xz,
      const float* __restrict__ dbc, const float* __restrict__ A_log,
      const float* __restrict__ Dp, float* __restrict__ y){
  __shared__ float dt_s[TP][8], xc_s[TP][8];
  __shared__ float Bs[TP][16], Cs[TP][16];
  __shared__ float Eb[8][128], Pb[8][128];
  int tid = threadIdx.x;
  int c = tid >> 7, gl = (tid >> 4) & 7, n = tid & 15;
  int dblk = blockIdx.x & 31, b = blockIdx.x >> 5;
  int d0 = dblk*8;
  size_t rbase = (size_t)b*TP;
  for(int u=tid; u<TP*8; u+=1024){
    int tt = u>>3, gg = u&7;
    size_t r = rbase + tt;
    dt_s[tt][gg] = dtb[r*DI + d0 + gg];
    xc_s[tt][gg] = xc [r*DI + d0 + gg];
  }
  for(int u=tid; u<TP*16; u+=1024){
    int tt = u>>4, nn = u&15;
    size_t r = rbase + tt;
    Bs[tt][nn] = dbc[r*40 + 8  + nn];
    Cs[tt][nn] = dbc[r*40 + 24 + nn];
  }
  __syncthreads();
  int d = d0 + gl;
  float An = -__expf(A_log[d*DS + n]);
  float h = 0.f, dtsum = 0.f;
  int tA = c*32;
  float hc[32], ev[32];
  #pragma unroll
  for(int i=0;i<32;i++){
    int t = tA + i;
    float dtv = dt_s[t][gl];
    dtsum += dtv;
    float e = __expf(dtv*An);
    ev[i] = e;
    h = fmaf(e, h, dtv*xc_s[t][gl]*Bs[t][n]);
    hc[i] = h*Cs[t][n];
  }
  Eb[c][gl*16+n] = h;
  Pb[c][gl*16+n] = __expf(An*dtsum);
  __syncthreads();
  float g = 0.f;
  for(int cp=0; cp<c; cp++)
    g = fmaf(Pb[cp][gl*16+n], g, Eb[cp][gl*16+n]);
  float Dpd = Dp[d];
  #pragma unroll
  for(int i=0;i<32;i++){
    int t = tA + i;
    g *= ev[i];
    float p = rsum16(hc[i] + g*Cs[t][n]);
    if(n==0){
      float zv = xz[(rbase+t)*512 + DI + d];
      float xcv = xc_s[t][gl];
      y[(rbase+t)*DI + d] = (p + Dpd*xcv) * fsilu(zv);
    }
  }
}

// ---------- out-proj GEMM + residual, h2-dot2 (last layer only).
__global__ __launch_bounds__(256) void k_out16h(const float* __restrict__ A,
    const uint32* __restrict__ Wh, float* __restrict__ C){
  __shared__ __align__(16) uint32 As2[8][20];
  __shared__ __align__(16) uint32 wsh[8][68];
  int tid = threadIdx.x;
  int n0 = blockIdx.x*64, m0 = blockIdx.y*16;
  int tx = tid&15, ty = tid>>4;
  float acc[4] = {};
  for(int kp0=0; kp0<128; kp0+=8){
    if(tid < 128){
      int row = tid>>3, kp = tid&7;
      float2 v = *(const float2*)(A + (size_t)(m0+row)*DI + (kp0+kp)*2);
      As2[kp][row] = pack_h2(v.x, v.y);
    } else {
      int u = tid-128; int n = u>>1, c4 = (u&1)*4;
      uint4 v = *(const uint4*)(Wh + (size_t)(n0+n)*128 + kp0 + c4);
      wsh[c4+0][n]=v.x; wsh[c4+1][n]=v.y; wsh[c4+2][n]=v.z; wsh[c4+3][n]=v.w;
    }
    __syncthreads();
    #pragma unroll
    for(int kp=0;kp<8;kp++){
      h2 a = as_h2(As2[kp][ty]);
      uint4 w4 = *(const uint4*)&wsh[kp][tx*4];
      acc[0] = __builtin_amdgcn_fdot2(a, as_h2(w4.x), acc[0], false);
      acc[1] = __builtin_amdgcn_fdot2(a, as_h2(w4.y), acc[1], false);
      acc[2] = __builtin_amdgcn_fdot2(a, as_h2(w4.z), acc[2], false);
      acc[3] = __builtin_amdgcn_fdot2(a, as_h2(w4.w), acc[3], false);
    }
    __syncthreads();
  }
  int m = m0 + ty;
  float* cp = &C[(size_t)m*DM + n0 + tx*4];
  cp[0] += acc[0]; cp[1] += acc[1]; cp[2] += acc[2]; cp[3] += acc[3];
}

// ---------- fused pre-LN + masked mean pool + classifier. grid 8, block 256.
__global__ __launch_bounds__(256) void k_head2(const float* __restrict__ h,
    const int* __restrict__ lengths, const float* __restrict__ g,
    const float* __restrict__ bv, const float* __restrict__ w1,
    const float* __restrict__ b1, const float* __restrict__ w2,
    const float* __restrict__ b2, float* __restrict__ out){
  __shared__ float pp[4][128];
  __shared__ float pooled[DM];
  __shared__ float cbuf[64];
  int b = blockIdx.x, tid = threadIdx.x;
  int lane = tid & 63, wv = tid >> 6;
  int tl = lengths[b] >> 1; if(tl < 1) tl = 1;
  float p0 = 0.f, p1 = 0.f;
  for(int t = wv; t < tl; t += 4){
    const float* row = h + ((size_t)(b*TP)+t)*DM;
    float v0 = row[lane], v1 = row[lane+64];
    float s = v0+v1;
    #pragma unroll
    for(int mm=32;mm>=1;mm>>=1) s += __shfl_xor(s,mm);
    float mean = s*(1.f/128.f);
    float e0 = v0-mean, e1 = v1-mean;
    float q = e0*e0+e1*e1;
    #pragma unroll
    for(int mm=32;mm>=1;mm>>=1) q += __shfl_xor(q,mm);
    float inv = rsqrtf(q*(1.f/128.f)+1e-5f);
    p0 += e0*inv*g[lane] + bv[lane];
    p1 += e1*inv*g[lane+64] + bv[lane+64];
  }
  pp[wv][lane] = p0; pp[wv][lane+64] = p1;
  __syncthreads();
  if(tid < 128)
    pooled[tid] = (pp[0][tid]+pp[1][tid]+pp[2][tid]+pp[3][tid]) / (float)tl;
  __syncthreads();
  if(tid < 64){
    float a = b1[tid];
    const float* wp = w1 + tid*DM;
    for(int k=0;k<DM;k++) a = fmaf(pooled[k], wp[k], a);
    cbuf[tid] = fsilu(a);
  }
  __syncthreads();
  if(tid < 35){
    float a = b2[tid];
    const float* wp = w2 + tid*64;
    for(int k=0;k<64;k++) a = fmaf(cbuf[k], wp[k], a);
    out[b*35+tid] = a;
  }
}

extern "C" void kernel_launch(void* const* d_in, const int* in_sizes, int n_in,
                              void* d_out, int out_size, void* d_ws, size_t ws_size,
                              hipStream_t stream){
  (void)in_sizes; (void)n_in; (void)out_size; (void)ws_size;
  const float* x        = (const float*)d_in[0];
  const int*   lengths  = (const int*)  d_in[1];
  const float* conv_w1  = (const float*)d_in[2];  const float* conv_b1 = (const float*)d_in[3];
  const float* bn1_s    = (const float*)d_in[4];  const float* bn1_b   = (const float*)d_in[5];
  const float* conv_w2  = (const float*)d_in[6];  const float* conv_b2 = (const float*)d_in[7];
  const float* bn2_s    = (const float*)d_in[8];  const float* bn2_b   = (const float*)d_in[9];
  const float* conv_w3  = (const float*)d_in[10]; const float* conv_b3 = (const float*)d_in[11];
  const float* bn3_s    = (const float*)d_in[12]; const float* bn3_b   = (const float*)d_in[13];
  const float* conv_w4  = (const float*)d_in[14]; const float* conv_b4 = (const float*)d_in[15];
  const float* bn4_s    = (const float*)d_in[16]; const float* bn4_b   = (const float*)d_in[17];
  const float* proj_w   = (const float*)d_in[18]; const float* proj_b  = (const float*)d_in[19];
  const float* proj_ln_s= (const float*)d_in[20]; const float* proj_ln_b=(const float*)d_in[21];
  const float* blk_ln_s = (const float*)d_in[22]; const float* blk_ln_b =(const float*)d_in[23];
  const float* in_w     = (const float*)d_in[24];
  const float* cw       = (const float*)d_in[25]; const float* cbv     = (const float*)d_in[26];
  const float* xp_w     = (const float*)d_in[27];
  const float* dt_w     = (const float*)d_in[28]; const float* dt_b    = (const float*)d_in[29];
  const float* A_log    = (const float*)d_in[30]; const float* Dp      = (const float*)d_in[31];
  const float* out_w    = (const float*)d_in[32];
  const float* pre_ln_s = (const float*)d_in[33]; const float* pre_ln_b= (const float*)d_in[34];
  const float* cls_w1   = (const float*)d_in[35]; const float* cls_b1  = (const float*)d_in[36];
  const float* cls_w2   = (const float*)d_in[37]; const float* cls_b2  = (const float*)d_in[38];

  float* ws   = (float*)d_ws;
  float* R0   = ws;                  // conv ping
  float* R1   = R0 + 16777216;       // conv pong / proj partials
  float* xT   = R1 + 16777216;
  float* hbuf = xT + 524288;
  float* lnb  = hbuf + 262144;       // spare
  float* xzb  = lnb + 262144;
  float* xcb  = xzb + 1048576;
  float* dbcb = xcb + 524288;
  float* dtbb = dbcb + 81920;
  float* yb   = dtbb + 524288;
  float* wt1  = yb + 524288;
  uint32* wt2h = (uint32*)(wt1 + 288);
  uint32* wt3h = wt2h + 4608;
  uint32* wt4h = wt3h + 9216;
  uint32* in_wh  = wt4h + 18432;         // 327,680
  uint32* out_wh = in_wh + 327680;       // 163,840

  // ---- weight transforms
  k_wt_all<<<96, 256, 0, stream>>>(conv_w1, conv_w2, conv_w4, wt1, wt2h, wt4h);
  k_wt3<<<36, 256, 0, stream>>>(conv_w3, wt3h);
  k_pack_w<<<1920, 256, 0, stream>>>(in_w, out_w, in_wh, out_wh);

  // ---- frontend
  k_transpose_x<<<2048, 256, 0, stream>>>(x, xT);
  k_conv_t4<1,32,8,1,1><<<8*8*32, 256, 0, stream>>>(xT, wt1, conv_b1, bn1_s, bn1_b, R0, 128, 512);
  k_conv_t7<16,32,8,8,1><<<8*8*32, 256, 0, stream>>>(R0, wt2h, conv_b2, bn2_s, bn2_b, R1, 128, 512);
  k_pool2x2<<<(8*32*64*256)/256, 256, 0, stream>>>(R1, R0, 32, 128, 512);
  k_conv_t7<16,64,8,8,2><<<8*4*16*2, 256, 0, stream>>>(R0, wt3h, conv_b3, bn3_s, bn3_b, R1, 64, 256);
  k_conv_t7<32,64,8,8,2><<<8*4*16*2, 256, 0, stream>>>(R1, wt4h, conv_b4, bn4_s, bn4_b, R0, 64, 256);

  // ---- fused pool(2,1) + projection GEMM (split-K x8)
  {
    dim3 gd(2, 64, 8);
    k_proj<<<gd, 256, 0, stream>>>(R0, proj_w, R1);
  }
  k_lnp<<<2048, 64, 0, stream>>>(R1, proj_b, proj_ln_s, proj_ln_b, hbuf);

  // ---- mamba layers (layer transitions fused via k_blk)
  { dim3 gd(8, 64);
    k_lnxz2<<<gd, 256, 0, stream>>>(hbuf, blk_ln_s, blk_ln_b, in_wh, xzb); }
  for(int i=0;i<NL;i++){
    k_xproj8<<<256, 256, 0, stream>>>(xzb, cw + (size_t)i*DI*4, cbv + i*DI,
                                      xp_w + (size_t)i*40*DI, dt_w + (size_t)i*DI*DTR,
                                      dt_b + i*DI, xcb, dbcb, dtbb);
    k_scan4<<<256, 1024, 0, stream>>>(dtbb, xcb, xzb, dbcb, A_log + (size_t)i*DI*DS, Dp + i*DI, yb);
    if(i < NL-1){
      k_blk<<<128, 256, 0, stream>>>(yb, out_wh + (size_t)i*128*128, hbuf,
                                     blk_ln_s + (i+1)*DM, blk_ln_b + (i+1)*DM,
                                     in_wh + (size_t)(i+1)*512*64, xzb);
    } else {
      dim3 gd(2, 128);
      k_out16h<<<gd, 256, 0, stream>>>(yb, out_wh + (size_t)i*128*128, hbuf);
    }
  }

  // ---- head (pre-LN fused)
  k_head2<<<8, 256, 0, stream>>>(hbuf, lengths, pre_ln_s, pre_ln_b,
                                 cls_w1, cls_b1, cls_w2, cls_b2, (float*)d_out);
}

// Round 16
// 1097.512 us; speedup vs baseline: 1.0903x; 1.0903x over previous
//
#include <hip/hip_runtime.h>
#include <math.h>

#define B_ 8
#define T_ 512
#define FEAT_ 128
#define TP 256          // T' after frontend
#define DM 128          // d_model
#define DI 256          // d_inner
#define DS 16           // d_state
#define DTR 8
#define NL 10

typedef _Float16 h2 __attribute__((ext_vector_type(2)));
typedef unsigned int uint32;

__device__ __forceinline__ float fsilu(float x){ return x / (1.f + __expf(-x)); }
__device__ __forceinline__ float fsoftplus(float x){ return (x > 20.f) ? x : log1pf(__expf(x)); }

__device__ __forceinline__ uint32 pack_h2(float a, float b){
  union { h2 h; uint32 u; } cv;
  cv.h[0] = (_Float16)a; cv.h[1] = (_Float16)b;   // RNE
  return cv.u;
}
__device__ __forceinline__ h2 as_h2(uint32 u){
  union { uint32 u; h2 h; } cv; cv.u = u; return cv.h;
}

// DPP row_ror move (16-lane row rotate), pure VALU — no LDS pipe.
template<int CTRL>
__device__ __forceinline__ float dpp_ror(float x){
  int v = __builtin_amdgcn_update_dpp(0, __float_as_int(x), CTRL, 0xF, 0xF, false);
  return __int_as_float(v);
}
__device__ __forceinline__ float rsum16(float x){
  x += dpp_ror<0x121>(x);
  x += dpp_ror<0x122>(x);
  x += dpp_ror<0x124>(x);
  x += dpp_ror<0x128>(x);
  return x;
}

// ---------- transpose x [8,512,128] -> xT [8,128,512]
__global__ void k_transpose_x(const float* __restrict__ x, float* __restrict__ xT){
  int idx = blockIdx.x*256 + threadIdx.x;
  if(idx >= B_*FEAT_*T_) return;
  int t = idx % T_; int f = (idx/T_) % FEAT_; int b = idx/(T_*FEAT_);
  xT[idx] = x[((size_t)b*T_ + t)*FEAT_ + f];
}

// ---------- conv weight transforms (packed h2 ci-pairs for conv2/3/4).
__device__ __forceinline__ void wt_pack(const float* __restrict__ w, uint32* __restrict__ o,
                                        int idx, int CO, int CIN){
  int CIN2 = CIN >> 1;
  int k = idx % 9; int ci2 = (idx/9) % CIN2; int co = idx/(9*CIN2);
  float f0 = w[((size_t)co*CIN + 2*ci2 + 0)*9 + k];
  float f1 = w[((size_t)co*CIN + 2*ci2 + 1)*9 + k];
  o[((size_t)(ci2*(CO>>3) + (co>>3)))*72 + (co&7)*9 + k] = pack_h2(f0, f1);
}
__global__ void k_wt_all(const float* __restrict__ w2, const float* __restrict__ w4,
                         uint32* __restrict__ o2, uint32* __restrict__ o4){
  int idx = blockIdx.x*256 + threadIdx.x;
  if(idx < 4608){ wt_pack(w2, o2, idx, 32, 32); return; }
  idx -= 4608;
  if(idx < 18432){ wt_pack(w4, o4, idx, 64, 64); return; }
}
__global__ void k_wt3(const float* __restrict__ w3, uint32* __restrict__ o3){
  int idx = blockIdx.x*256 + threadIdx.x;
  if(idx < 9216) wt_pack(w3, o3, idx, 64, 32);
}

// ---------- pack mamba GEMM weights to h2 (K-pairs), all layers.
__global__ void k_pack_w(const float* __restrict__ in_w, const float* __restrict__ out_w,
                         uint32* __restrict__ in_wh, uint32* __restrict__ out_wh){
  int idx = blockIdx.x*256 + threadIdx.x;
  int tot1 = NL*512*64;
  if(idx < tot1){
    const float* w = in_w + (size_t)idx*2;
    in_wh[idx] = pack_h2(w[0], w[1]);
    return;
  }
  idx -= tot1;
  if(idx < NL*128*128){
    const float* w = out_w + (size_t)idx*2;
    out_wh[idx] = pack_h2(w[0], w[1]);
  }
}

// ---------- FUSED conv1(fp32)+BN+SiLU -> conv2(f16-dot2)+BN+SiLU.
// Per 16x16 tile: stage 20x20 input (2-halo), conv1 all 32 ch in-LDS (packed
// h2 pairs, OOB rows/cols zeroed = SAME pad), then conv2 with all 16 ci2
// resident. Grid 2048 (b8 x hpr8 x wpr32), 256 thr.
// R15 BUG FIX: w1s staging now grid-strided (288 > 256 threads).
__global__ __launch_bounds__(256) void k_conv12(const float* __restrict__ xT,
     const float* __restrict__ w1, const float* __restrict__ cb1,
     const float* __restrict__ bs1, const float* __restrict__ bb1,
     const uint32* __restrict__ wt2, const float* __restrict__ cb2,
     const float* __restrict__ bs2, const float* __restrict__ bb2,
     float* __restrict__ out){
  const int H = 128, W = 512;
  __shared__ __align__(16) float xin[400];        // 20x20 input tile
  __shared__ __align__(16) uint32 c1pk[16*360];   // conv1-out packed [ci2][18][20]
  __shared__ float w1s[288];
  __shared__ float bn1s[32], bn1b[32];
  int tid = threadIdx.x;
  int lane = tid & 63;
  int wav = __builtin_amdgcn_readfirstlane(tid >> 6);
  int idx = blockIdx.x;
  int tj = idx % 32; idx /= 32;
  int ti = idx % 8;  int b = idx / 8;
  int i0 = ti*16, j0 = tj*16;
  for(int u=tid; u<288; u+=256) w1s[u] = w1[u];   // FIXED (was if(tid<288))
  if(tid < 32){ float s = bs1[tid]; bn1s[tid] = s; bn1b[tid] = cb1[tid]*s + bb1[tid]; }
  for(int u=tid; u<400; u+=256){
    int rr = u/20, cc = u - rr*20;
    int gi = i0 - 2 + rr, gj = j0 - 2 + cc;
    float v = 0.f;
    if(gi >= 0 && gi < H && gj >= 0 && gj < W)
      v = xT[((size_t)b*H + gi)*W + gj];
    xin[rr*20+cc] = v;
  }
  __syncthreads();
  // conv1 + BN + SiLU, packed pairs; zero outside image (SAME-pad for conv2)
  for(int u=tid; u<324*16; u+=256){
    int ci2 = u/324; int pos = u - ci2*324; int rr = pos/18, cc = pos - rr*18;
    int gi = i0 - 1 + rr, gj = j0 - 1 + cc;
    float v0 = 0.f, v1 = 0.f;
    if(gi >= 0 && gi < H && gj >= 0 && gj < W){
      int c0 = 2*ci2, c1 = 2*ci2+1;
      float a0 = 0.f, a1 = 0.f;
      #pragma unroll
      for(int kh=0;kh<3;kh++)
        #pragma unroll
        for(int kw=0;kw<3;kw++){
          float xv = xin[(rr+kh)*20 + cc+kw];
          a0 = fmaf(w1s[c0*9 + kh*3 + kw], xv, a0);
          a1 = fmaf(w1s[c1*9 + kh*3 + kw], xv, a1);
        }
      v0 = fsilu(a0*bn1s[c0] + bn1b[c0]);
      v1 = fsilu(a1*bn1s[c1] + bn1b[c1]);
    }
    c1pk[ci2*360 + rr*20 + cc] = pack_h2(v0, v1);
  }
  __syncthreads();
  // conv2 dot2 (t7 lane map/weight layout, NS=4, wslot=wav)
  int r = lane & 15, cg = lane >> 4;
  const uint32* wbase = wt2 + (size_t)wav*72;
  float acc[8][4] = {};
  for(int ci2=0; ci2<16; ci2++){
    const uint4* wp4 = (const uint4*)(wbase + (size_t)ci2*(4*72));
    uint4 w4q[18];
    #pragma unroll
    for(int q=0;q<18;q++) w4q[q] = wp4[q];
    const uint32* wf = (const uint32*)w4q;
    h2 v[3][6];
    #pragma unroll
    for(int kh=0;kh<3;kh++){
      const uint32* trow = &c1pk[ci2*360 + (r+kh)*20 + cg*4];
      uint4 a4 = *(const uint4*)trow;
      v[kh][0]=as_h2(a4.x); v[kh][1]=as_h2(a4.y);
      v[kh][2]=as_h2(a4.z); v[kh][3]=as_h2(a4.w);
      v[kh][4]=as_h2(trow[4]); v[kh][5]=as_h2(trow[5]);
    }
    #pragma unroll
    for(int co=0;co<8;co++){
      #pragma unroll
      for(int kh=0;kh<3;kh++){
        #pragma unroll
        for(int kw=0;kw<3;kw++){
          h2 wv = as_h2(wf[co*9 + kh*3 + kw]);
          #pragma unroll
          for(int u2=0;u2<4;u2++)
            acc[co][u2] = __builtin_amdgcn_fdot2(wv, v[kh][kw+u2], acc[co][u2], false);
        }
      }
    }
  }
  int i = i0 + r;
  #pragma unroll
  for(int co=0; co<8; co++){
    int c = wav*8 + co;
    float s = bs2[c], bias = cb2[c]*s + bb2[c];
    float4 o;
    o.x = fsilu(acc[co][0]*s + bias);
    o.y = fsilu(acc[co][1]*s + bias);
    o.z = fsilu(acc[co][2]*s + bias);
    o.w = fsilu(acc[co][3]*s + bias);
    *(float4*)&out[((size_t)(b*32 + c)*H + i)*W + j0 + cg*4] = o;
  }
}

// ---------- f16-dot2 direct conv (t7b): CIG2=8, reg-staged prefetch pipeline.
template<int CIN2, int CO, int CPW, int CIG2, int COG>
__global__ __launch_bounds__(256) void k_conv_t7(const float* __restrict__ in,
     const uint32* __restrict__ wt, const float* __restrict__ cb,
     const float* __restrict__ bs, const float* __restrict__ bb,
     float* __restrict__ out, int H, int W){
  constexpr int NS = CO/CPW;
  constexpr int NSLAB = CIN2/CIG2;
  constexpr int NEL = CIG2*324;
  constexpr int NLD = (NEL + 255)/256;
  __shared__ __align__(16) uint32 tile[CIG2*360];
  int tid = threadIdx.x;
  int lane = tid & 63;
  int wav = __builtin_amdgcn_readfirstlane(tid >> 6);
  int wpr = W >> 4, hpr = H >> 4;
  int idx = blockIdx.x;
  int cog = idx % COG; idx /= COG;
  int tj = idx % wpr; idx /= wpr;
  int ti = idx % hpr; int b = idx / hpr;
  int i0 = ti*16, j0 = tj*16;
  int r = lane & 15, cg = lane >> 4;
  int wslot = cog*4 + wav;
  const uint32* wbase = wt + (size_t)wslot*72;
  float acc[CPW][4] = {};
  float r0[NLD], r1[NLD];

  auto LOAD = [&](int c2g){
    #pragma unroll
    for(int l=0;l<NLD;l++){
      int u = tid + l*256;
      float v0 = 0.f, v1 = 0.f;
      if(u < NEL){
        int ci2 = u/324; int rem = u - ci2*324; int rr = rem/18; int cc = rem - rr*18;
        int gi = i0 - 1 + rr, gj = j0 - 1 + cc;
        if(gi >= 0 && gi < H && gj >= 0 && gj < W){
          const float* p = in + ((size_t)(b*(CIN2*2) + (c2g+ci2)*2)*H + gi)*W + gj;
          v0 = p[0];
          v1 = p[(size_t)H*W];
        }
      }
      r0[l] = v0; r1[l] = v1;
    }
  };
  auto WRITE = [&](){
    #pragma unroll
    for(int l=0;l<NLD;l++){
      int u = tid + l*256;
      if(u < NEL){
        int ci2 = u/324; int rem = u - ci2*324; int rr = rem/18; int cc = rem - rr*18;
        tile[ci2*360 + rr*20 + cc] = pack_h2(r0[l], r1[l]);
      }
    }
  };

  LOAD(0);
  for(int s=0; s<NSLAB; s++){
    __syncthreads();
    WRITE();
    __syncthreads();
    if(s+1 < NSLAB) LOAD((s+1)*CIG2);
    #pragma unroll
    for(int ci2=0; ci2<CIG2; ci2++){
      int sci2 = s*CIG2 + ci2;
      const uint4* wp4 = (const uint4*)(wbase + (size_t)sci2*(NS*72));
      uint4 w4q[18];
      #pragma unroll
      for(int q=0;q<18;q++) w4q[q] = wp4[q];
      const uint32* wf = (const uint32*)w4q;
      h2 v[3][6];
      #pragma unroll
      for(int kh=0;kh<3;kh++){
        const uint32* trow = &tile[ci2*360 + (r+kh)*20 + cg*4];
        uint4 a4 = *(const uint4*)trow;
        v[kh][0]=as_h2(a4.x); v[kh][1]=as_h2(a4.y);
        v[kh][2]=as_h2(a4.z); v[kh][3]=as_h2(a4.w);
        v[kh][4]=as_h2(trow[4]); v[kh][5]=as_h2(trow[5]);
      }
      #pragma unroll
      for(int co=0;co<CPW;co++){
        #pragma unroll
        for(int kh=0;kh<3;kh++){
          #pragma unroll
          for(int kw=0;kw<3;kw++){
            h2 wv = as_h2(wf[co*9 + kh*3 + kw]);
            #pragma unroll
            for(int u2=0;u2<4;u2++)
              acc[co][u2] = __builtin_amdgcn_fdot2(wv, v[kh][kw+u2], acc[co][u2], false);
          }
        }
      }
    }
  }
  int i = i0 + r;
  #pragma unroll
  for(int co=0; co<CPW; co++){
    int c = cog*(4*CPW) + wav*CPW + co;
    float s = bs[c], bias = cb[c]*s + bb[c];
    float4 o;
    o.x = fsilu(acc[co][0]*s + bias);
    o.y = fsilu(acc[co][1]*s + bias);
    o.z = fsilu(acc[co][2]*s + bias);
    o.w = fsilu(acc[co][3]*s + bias);
    *(float4*)&out[((size_t)(b*CO + c)*H + i)*W + j0 + cg*4] = o;
  }
}

// ---------- 2x2 max pool stride 2
__global__ void k_pool2x2(const float* __restrict__ in, float* __restrict__ out,
                          int C, int Hi, int Wi){
  int Ho = Hi>>1, Wo = Wi>>1;
  int total = B_*C*Ho*Wo;
  int idx = blockIdx.x*256 + threadIdx.x;
  if(idx >= total) return;
  int j = idx % Wo; int i = (idx/Wo)%Ho; int c = (idx/(Wo*Ho))%C; int b = idx/(Wo*Ho*C);
  const float* p = in + (((size_t)(b*C+c)*Hi + 2*i)*Wi + 2*j);
  out[idx] = fmaxf(fmaxf(p[0], p[1]), fmaxf(p[Wi], p[Wi+1]));
}

// ---------- fused (2,1)-maxpool + proj GEMM, split-K x8.
__global__ __launch_bounds__(256) void k_proj(const float* __restrict__ R0,
    const float* __restrict__ W, float* __restrict__ pbuf){
  __shared__ __align__(16) float As[16][33];
  __shared__ __align__(16) float Ws[16][68];
  int tid = threadIdx.x;
  int n0 = blockIdx.x*64, m0 = blockIdx.y*32;
  int kc = blockIdx.z;
  int b = m0 >> 8;
  int t_base = m0 & 255;
  int tx = tid&15, ty = tid>>4;
  float acc[2][4] = {};
  for(int k0=0; k0<256; k0+=16){
    int kg0 = kc*256 + k0;
    if(tid < 128){
      int row = tid>>2, cq = (tid&3)*4;
      #pragma unroll
      for(int c2=0;c2<4;c2++){
        int k = kg0 + cq + c2;
        int c = k>>5, hh = k&31;
        const float* p = R0 + (((size_t)(b*64+c)*64 + 2*hh)*256 + t_base + row);
        As[cq+c2][row] = fmaxf(p[0], p[256]);
      }
    } else {
      int u = tid - 128; int n = u>>1, cq = (u&1)*8;
      const float* wp = W + (size_t)(n0+n)*2048 + kg0 + cq;
      float4 v0 = *(const float4*)wp, v1 = *(const float4*)(wp+4);
      Ws[cq+0][n]=v0.x; Ws[cq+1][n]=v0.y; Ws[cq+2][n]=v0.z; Ws[cq+3][n]=v0.w;
      Ws[cq+4][n]=v1.x; Ws[cq+5][n]=v1.y; Ws[cq+6][n]=v1.z; Ws[cq+7][n]=v1.w;
    }
    __syncthreads();
    #pragma unroll
    for(int kk=0;kk<16;kk++){
      float a0 = As[kk][ty*2+0];
      float a1 = As[kk][ty*2+1];
      float4 w4 = *(const float4*)&Ws[kk][tx*4];
      float wv4[4] = {w4.x,w4.y,w4.z,w4.w};
      #pragma unroll
      for(int j=0;j<4;j++){
        acc[0][j] = fmaf(a0, wv4[j], acc[0][j]);
        acc[1][j] = fmaf(a1, wv4[j], acc[1][j]);
      }
    }
    __syncthreads();
  }
  float* pb = pbuf + (size_t)kc*2048*DM;
  #pragma unroll
  for(int iu=0;iu<2;iu++){
    int m = m0 + ty*2 + iu;
    #pragma unroll
    for(int j=0;j<4;j++){
      int n = n0 + tx*4 + j;
      pb[(size_t)m*DM + n] = acc[iu][j];
    }
  }
}

// ---------- reduce 8 split-K partials + bias + LN + SiLU -> hbuf. 1 wave/row.
__global__ void k_lnp(const float* __restrict__ pbuf, const float* __restrict__ bias,
                      const float* __restrict__ g, const float* __restrict__ b,
                      float* __restrict__ out){
  int row = blockIdx.x;
  int t = threadIdx.x; // 64
  float v0 = bias[t], v1 = bias[t+64];
  #pragma unroll
  for(int kc=0;kc<8;kc++){
    const float* p = pbuf + ((size_t)kc*2048 + row)*DM;
    v0 += p[t]; v1 += p[t+64];
  }
  float s = v0 + v1;
  #pragma unroll
  for(int m=32;m>=1;m>>=1) s += __shfl_xor(s, m);
  float mean = s * (1.f/128.f);
  float e0 = v0-mean, e1 = v1-mean;
  float q = e0*e0 + e1*e1;
  #pragma unroll
  for(int m=32;m>=1;m>>=1) q += __shfl_xor(q, m);
  float inv = rsqrtf(q*(1.f/128.f) + 1e-5f);
  float o0 = fsilu(e0*inv*g[t] + b[t]);
  float o1 = fsilu(e1*inv*g[t+64] + b[t+64]);
  float* po = out + (size_t)row*DM;
  po[t] = o0; po[t+64] = o1;
}

// ---------- fused LN + xz GEMM, h2-dot2.
__global__ __launch_bounds__(256) void k_lnxz2(const float* __restrict__ hbuf,
    const float* __restrict__ g, const float* __restrict__ bb,
    const uint32* __restrict__ Wh, float* __restrict__ out){
  __shared__ __align__(16) float lns[32][132];
  __shared__ __align__(16) uint32 ah[32][68];
  __shared__ __align__(16) uint32 wsh[8][68];
  int tid = threadIdx.x;
  int n0 = blockIdx.x*64, m0 = blockIdx.y*32;
  for(int u=tid; u<1024; u+=256){
    int row = u>>5, c4 = (u&31)*4;
    float4 v = *(const float4*)(hbuf + (size_t)(m0+row)*DM + c4);
    lns[row][c4] = v.x; lns[row][c4+1] = v.y; lns[row][c4+2] = v.z; lns[row][c4+3] = v.w;
  }
  __syncthreads();
  {
    int lane = tid & 63, wv = tid >> 6;
    for(int rr = wv; rr < 32; rr += 4){
      float v0 = lns[rr][lane], v1 = lns[rr][lane+64];
      float s = v0+v1;
      #pragma unroll
      for(int mm=32;mm>=1;mm>>=1) s += __shfl_xor(s,mm);
      float mean = s*(1.f/128.f);
      float e0 = v0-mean, e1 = v1-mean;
      float q = e0*e0+e1*e1;
      #pragma unroll
      for(int mm=32;mm>=1;mm>>=1) q += __shfl_xor(q,mm);
      float inv = rsqrtf(q*(1.f/128.f)+1e-5f);
      lns[rr][lane]    = e0*inv*g[lane] + bb[lane];
      lns[rr][lane+64] = e1*inv*g[lane+64] + bb[lane+64];
    }
  }
  __syncthreads();
  for(int u=tid; u<32*64; u+=256){
    int row = u>>6, p = u&63;
    ah[row][p] = pack_h2(lns[row][2*p], lns[row][2*p+1]);
  }
  __syncthreads();
  int tx = tid&15, ty = tid>>4;
  float acc[2][4] = {};
  for(int kp0=0; kp0<64; kp0+=8){
    {
      int n = tid>>2, c = (tid&3)*2;
      uint2 v = *(const uint2*)(Wh + (size_t)(n0+n)*64 + kp0 + c);
      wsh[c+0][n] = v.x; wsh[c+1][n] = v.y;
    }
    __syncthreads();
    #pragma unroll
    for(int kp=0;kp<8;kp++){
      h2 a0 = as_h2(ah[ty*2+0][kp0+kp]);
      h2 a1 = as_h2(ah[ty*2+1][kp0+kp]);
      uint4 w4 = *(const uint4*)&wsh[kp][tx*4];
      acc[0][0] = __builtin_amdgcn_fdot2(a0, as_h2(w4.x), acc[0][0], false);
      acc[0][1] = __builtin_amdgcn_fdot2(a0, as_h2(w4.y), acc[0][1], false);
      acc[0][2] = __builtin_amdgcn_fdot2(a0, as_h2(w4.z), acc[0][2], false);
      acc[0][3] = __builtin_amdgcn_fdot2(a0, as_h2(w4.w), acc[0][3], false);
      acc[1][0] = __builtin_amdgcn_fdot2(a1, as_h2(w4.x), acc[1][0], false);
      acc[1][1] = __builtin_amdgcn_fdot2(a1, as_h2(w4.y), acc[1][1], false);
      acc[1][2] = __builtin_amdgcn_fdot2(a1, as_h2(w4.z), acc[1][2], false);
      acc[1][3] = __builtin_amdgcn_fdot2(a1, as_h2(w4.w), acc[1][3], false);
    }
    __syncthreads();
  }
  #pragma unroll
  for(int iu=0;iu<2;iu++){
    int m = m0 + ty*2 + iu;
    float* po = out + (size_t)m*512 + n0 + tx*4;
    #pragma unroll
    for(int j=0;j<4;j++) po[j] = acc[iu][j];
  }
}

// ---------- fused: causal dwconv(4)+SiLU -> dbc GEMM -> dt GEMM+softplus.
__global__ __launch_bounds__(256) void k_xproj8(const float* __restrict__ xz,
    const float* __restrict__ cw, const float* __restrict__ cb,
    const float* __restrict__ xpw, const float* __restrict__ dtw,
    const float* __restrict__ dtb_, float* __restrict__ xc_g,
    float* __restrict__ dbc_g, float* __restrict__ dt_g){
  __shared__ float xzs[11][64];
  __shared__ float As[64][9];
  __shared__ float Wp[64][41];
  __shared__ float dtin[8][9];
  __shared__ float dtw_s[256][9];
  int tid = threadIdx.x;
  int row0 = blockIdx.x*8; int b = row0 >> 8; int t0 = row0 & 255;
  int rA = tid & 7, cgA = tid >> 3;
  int dlC = tid & 63, rqC = tid >> 6;
  float acc0 = 0.f, acc1 = 0.f;
  for(int ch=0; ch<4; ch++){
    int d0 = ch*64;
    __syncthreads();
    for(int u=tid; u<11*64; u+=256){
      int rr = u>>6, dl = u&63;
      int t = t0 + rr - 3;
      xzs[rr][dl] = (t >= 0) ? xz[((size_t)(b*TP)+t)*512 + d0 + dl] : 0.f;
    }
    for(int u=tid; u<40*64; u+=256){
      int nn = u>>6, dk = u&63;
      Wp[dk][nn] = xpw[(size_t)nn*DI + d0 + dk];
    }
    __syncthreads();
    {
      float cw0 = cw[(d0+dlC)*4+0], cw1 = cw[(d0+dlC)*4+1];
      float cw2 = cw[(d0+dlC)*4+2], cw3 = cw[(d0+dlC)*4+3];
      float cbv = cb[d0+dlC];
      #pragma unroll
      for(int i=0;i<2;i++){
        int rr = rqC*2 + i;
        float a = cbv;
        a = fmaf(cw0, xzs[rr+0][dlC], a);
        a = fmaf(cw1, xzs[rr+1][dlC], a);
        a = fmaf(cw2, xzs[rr+2][dlC], a);
        a = fmaf(cw3, xzs[rr+3][dlC], a);
        float v = fsilu(a);
        As[dlC][rr] = v;
        xc_g[((size_t)row0 + rr)*DI + d0 + dlC] = v;
      }
    }
    __syncthreads();
    for(int dk=0; dk<64; dk++){
      float a = As[dk][rA];
      acc0 = fmaf(a, Wp[dk][cgA], acc0);
      if(cgA < 8) acc1 = fmaf(a, Wp[dk][cgA+32], acc1);
    }
  }
  if(cgA < 8){
    dtin[rA][cgA] = acc0;
    dbc_g[((size_t)row0 + rA)*40 + cgA + 32] = acc1;
  } else {
    dbc_g[((size_t)row0 + rA)*40 + cgA] = acc0;
  }
  for(int u=tid; u<256*8; u+=256) dtw_s[u>>3][u&7] = dtw[u];
  __syncthreads();
  {
    int d = tid;
    float bias = dtb_[d];
    float w8[8];
    #pragma unroll
    for(int k=0;k<8;k++) w8[k] = dtw_s[d][k];
    #pragma unroll
    for(int r2=0;r2<8;r2++){
      float a = bias;
      #pragma unroll
      for(int k=0;k<8;k++) a = fmaf(dtin[r2][k], w8[k], a);
      dt_g[((size_t)row0 + r2)*DI + d] = fsoftplus(a);
    }
  }
}

// ---------- chunked selective scan v4: 8 chunks of 32, block 1024 thr, DPP reduce.
__global__ __launch_bounds__(1024) void k_scan4(const float* __restrict__ dtb,
      const float* __restrict__ xc, const float* __restrict__ xz,
      const float* __restrict__ dbc, const float* __restrict__ A_log,
      const float* __restrict__ Dp, float* __restrict__ y){
  __shared__ float dt_s[TP][8], xc_s[TP][8];
  __shared__ float Bs[TP][16], Cs[TP][16];
  __shared__ float Eb[8][128], Pb[8][128];
  int tid = threadIdx.x;
  int c = tid >> 7, gl = (tid >> 4) & 7, n = tid & 15;
  int dblk = blockIdx.x & 31, b = blockIdx.x >> 5;
  int d0 = dblk*8;
  size_t rbase = (size_t)b*TP;
  for(int u=tid; u<TP*8; u+=1024){
    int tt = u>>3, gg = u&7;
    size_t r = rbase + tt;
    dt_s[tt][gg] = dtb[r*DI + d0 + gg];
    xc_s[tt][gg] = xc [r*DI + d0 + gg];
  }
  for(int u=tid; u<TP*16; u+=1024){
    int tt = u>>4, nn = u&15;
    size_t r = rbase + tt;
    Bs[tt][nn] = dbc[r*40 + 8  + nn];
    Cs[tt][nn] = dbc[r*40 + 24 + nn];
  }
  __syncthreads();
  int d = d0 + gl;
  float An = -__expf(A_log[d*DS + n]);
  float h = 0.f, dtsum = 0.f;
  int tA = c*32;
  float hc[32], ev[32];
  #pragma unroll
  for(int i=0;i<32;i++){
    int t = tA + i;
    float dtv = dt_s[t][gl];
    dtsum += dtv;
    float e = __expf(dtv*An);
    ev[i] = e;
    h = fmaf(e, h, dtv*xc_s[t][gl]*Bs[t][n]);
    hc[i] = h*Cs[t][n];
  }
  Eb[c][gl*16+n] = h;
  Pb[c][gl*16+n] = __expf(An*dtsum);
  __syncthreads();
  float g = 0.f;
  for(int cp=0; cp<c; cp++)
    g = fmaf(Pb[cp][gl*16+n], g, Eb[cp][gl*16+n]);
  float Dpd = Dp[d];
  #pragma unroll
  for(int i=0;i<32;i++){
    int t = tA + i;
    g *= ev[i];
    float p = rsum16(hc[i] + g*Cs[t][n]);
    if(n==0){
      float zv = xz[(rbase+t)*512 + DI + d];
      float xcv = xc_s[t][gl];
      y[(rbase+t)*DI + d] = (p + Dpd*xcv) * fsilu(zv);
    }
  }
}

// ---------- out-proj GEMM + residual, h2-dot2: 16-row tiles, grid (2, 128).
__global__ __launch_bounds__(256) void k_out16h(const float* __restrict__ A,
    const uint32* __restrict__ Wh, float* __restrict__ C){
  __shared__ __align__(16) uint32 As2[8][20];
  __shared__ __align__(16) uint32 wsh[8][68];
  int tid = threadIdx.x;
  int n0 = blockIdx.x*64, m0 = blockIdx.y*16;
  int tx = tid&15, ty = tid>>4;
  float acc[4] = {};
  for(int kp0=0; kp0<128; kp0+=8){
    if(tid < 128){
      int row = tid>>3, kp = tid&7;
      float2 v = *(const float2*)(A + (size_t)(m0+row)*DI + (kp0+kp)*2);
      As2[kp][row] = pack_h2(v.x, v.y);
    } else {
      int u = tid-128; int n = u>>1, c4 = (u&1)*4;
      uint4 v = *(const uint4*)(Wh + (size_t)(n0+n)*128 + kp0 + c4);
      wsh[c4+0][n]=v.x; wsh[c4+1][n]=v.y; wsh[c4+2][n]=v.z; wsh[c4+3][n]=v.w;
    }
    __syncthreads();
    #pragma unroll
    for(int kp=0;kp<8;kp++){
      h2 a = as_h2(As2[kp][ty]);
      uint4 w4 = *(const uint4*)&wsh[kp][tx*4];
      acc[0] = __builtin_amdgcn_fdot2(a, as_h2(w4.x), acc[0], false);
      acc[1] = __builtin_amdgcn_fdot2(a, as_h2(w4.y), acc[1], false);
      acc[2] = __builtin_amdgcn_fdot2(a, as_h2(w4.z), acc[2], false);
      acc[3] = __builtin_amdgcn_fdot2(a, as_h2(w4.w), acc[3], false);
    }
    __syncthreads();
  }
  int m = m0 + ty;
  float* cp = &C[(size_t)m*DM + n0 + tx*4];
  cp[0] += acc[0]; cp[1] += acc[1]; cp[2] += acc[2]; cp[3] += acc[3];
}

// ---------- fused pre-LN + masked mean pool + classifier. grid 8, block 256.
__global__ __launch_bounds__(256) void k_head2(const float* __restrict__ h,
    const int* __restrict__ lengths, const float* __restrict__ g,
    const float* __restrict__ bv, const float* __restrict__ w1,
    const float* __restrict__ b1, const float* __restrict__ w2,
    const float* __restrict__ b2, float* __restrict__ out){
  __shared__ float pp[4][128];
  __shared__ float pooled[DM];
  __shared__ float cbuf[64];
  int b = blockIdx.x, tid = threadIdx.x;
  int lane = tid & 63, wv = tid >> 6;
  int tl = lengths[b] >> 1; if(tl < 1) tl = 1;
  float p0 = 0.f, p1 = 0.f;
  for(int t = wv; t < tl; t += 4){
    const float* row = h + ((size_t)(b*TP)+t)*DM;
    float v0 = row[lane], v1 = row[lane+64];
    float s = v0+v1;
    #pragma unroll
    for(int mm=32;mm>=1;mm>>=1) s += __shfl_xor(s,mm);
    float mean = s*(1.f/128.f);
    float e0 = v0-mean, e1 = v1-mean;
    float q = e0*e0+e1*e1;
    #pragma unroll
    for(int mm=32;mm>=1;mm>>=1) q += __shfl_xor(q,mm);
    float inv = rsqrtf(q*(1.f/128.f)+1e-5f);
    p0 += e0*inv*g[lane] + bv[lane];
    p1 += e1*inv*g[lane+64] + bv[lane+64];
  }
  pp[wv][lane] = p0; pp[wv][lane+64] = p1;
  __syncthreads();
  if(tid < 128)
    pooled[tid] = (pp[0][tid]+pp[1][tid]+pp[2][tid]+pp[3][tid]) / (float)tl;
  __syncthreads();
  if(tid < 64){
    float a = b1[tid];
    const float* wp = w1 + tid*DM;
    for(int k=0;k<DM;k++) a = fmaf(pooled[k], wp[k], a);
    cbuf[tid] = fsilu(a);
  }
  __syncthreads();
  if(tid < 35){
    float a = b2[tid];
    const float* wp = w2 + tid*64;
    for(int k=0;k<64;k++) a = fmaf(cbuf[k], wp[k], a);
    out[b*35+tid] = a;
  }
}

extern "C" void kernel_launch(void* const* d_in, const int* in_sizes, int n_in,
                              void* d_out, int out_size, void* d_ws, size_t ws_size,
                              hipStream_t stream){
  (void)in_sizes; (void)n_in; (void)out_size; (void)ws_size;
  const float* x        = (const float*)d_in[0];
  const int*   lengths  = (const int*)  d_in[1];
  const float* conv_w1  = (const float*)d_in[2];  const float* conv_b1 = (const float*)d_in[3];
  const float* bn1_s    = (const float*)d_in[4];  const float* bn1_b   = (const float*)d_in[5];
  const float* conv_w2  = (const float*)d_in[6];  const float* conv_b2 = (const float*)d_in[7];
  const float* bn2_s    = (const float*)d_in[8];  const float* bn2_b   = (const float*)d_in[9];
  const float* conv_w3  = (const float*)d_in[10]; const float* conv_b3 = (const float*)d_in[11];
  const float* bn3_s    = (const float*)d_in[12]; const float* bn3_b   = (const float*)d_in[13];
  const float* conv_w4  = (const float*)d_in[14]; const float* conv_b4 = (const float*)d_in[15];
  const float* bn4_s    = (const float*)d_in[16]; const float* bn4_b   = (const float*)d_in[17];
  const float* proj_w   = (const float*)d_in[18]; const float* proj_b  = (const float*)d_in[19];
  const float* proj_ln_s= (const float*)d_in[20]; const float* proj_ln_b=(const float*)d_in[21];
  const float* blk_ln_s = (const float*)d_in[22]; const float* blk_ln_b =(const float*)d_in[23];
  const float* in_w     = (const float*)d_in[24];
  const float* cw       = (const float*)d_in[25]; const float* cbv     = (const float*)d_in[26];
  const float* xp_w     = (const float*)d_in[27];
  const float* dt_w     = (const float*)d_in[28]; const float* dt_b    = (const float*)d_in[29];
  const float* A_log    = (const float*)d_in[30]; const float* Dp      = (const float*)d_in[31];
  const float* out_w    = (const float*)d_in[32];
  const float* pre_ln_s = (const float*)d_in[33]; const float* pre_ln_b= (const float*)d_in[34];
  const float* cls_w1   = (const float*)d_in[35]; const float* cls_b1  = (const float*)d_in[36];
  const float* cls_w2   = (const float*)d_in[37]; const float* cls_b2  = (const float*)d_in[38];

  float* ws   = (float*)d_ws;
  float* R0   = ws;                  // conv ping
  float* R1   = R0 + 16777216;       // conv pong / proj partials
  float* xT   = R1 + 16777216;
  float* hbuf = xT + 524288;
  float* lnb  = hbuf + 262144;       // spare
  float* xzb  = lnb + 262144;
  float* xcb  = xzb + 1048576;
  float* dbcb = xcb + 524288;
  float* dtbb = dbcb + 81920;
  float* yb   = dtbb + 524288;
  uint32* wt2h = (uint32*)(yb + 524288);
  uint32* wt3h = wt2h + 4608;
  uint32* wt4h = wt3h + 9216;
  uint32* in_wh  = wt4h + 18432;         // 327,680
  uint32* out_wh = in_wh + 327680;       // 163,840

  // ---- weight transforms
  k_wt_all<<<90, 256, 0, stream>>>(conv_w2, conv_w4, wt2h, wt4h);
  k_wt3<<<36, 256, 0, stream>>>(conv_w3, wt3h);
  k_pack_w<<<1920, 256, 0, stream>>>(in_w, out_w, in_wh, out_wh);

  // ---- frontend (conv1+conv2 fused)
  k_transpose_x<<<2048, 256, 0, stream>>>(x, xT);
  k_conv12<<<2048, 256, 0, stream>>>(xT, conv_w1, conv_b1, bn1_s, bn1_b,
                                     wt2h, conv_b2, bn2_s, bn2_b, R1);
  k_pool2x2<<<(8*32*64*256)/256, 256, 0, stream>>>(R1, R0, 32, 128, 512);
  k_conv_t7<16,64,8,8,2><<<8*4*16*2, 256, 0, stream>>>(R0, wt3h, conv_b3, bn3_s, bn3_b, R1, 64, 256);
  k_conv_t7<32,64,8,8,2><<<8*4*16*2, 256, 0, stream>>>(R1, wt4h, conv_b4, bn4_s, bn4_b, R0, 64, 256);

  // ---- fused pool(2,1) + projection GEMM (split-K x8)
  {
    dim3 gd(2, 64, 8);
    k_proj<<<gd, 256, 0, stream>>>(R0, proj_w, R1);
  }
  k_lnp<<<2048, 64, 0, stream>>>(R1, proj_b, proj_ln_s, proj_ln_b, hbuf);

  // ---- mamba layers (R13 structure)
  for(int i=0;i<NL;i++){
    { dim3 gd(8, 64);
      k_lnxz2<<<gd, 256, 0, stream>>>(hbuf, blk_ln_s + i*DM, blk_ln_b + i*DM,
                                      in_wh + (size_t)i*512*64, xzb); }
    k_xproj8<<<256, 256, 0, stream>>>(xzb, cw + (size_t)i*DI*4, cbv + i*DI,
                                      xp_w + (size_t)i*40*DI, dt_w + (size_t)i*DI*DTR,
                                      dt_b + i*DI, xcb, dbcb, dtbb);
    k_scan4<<<256, 1024, 0, stream>>>(dtbb, xcb, xzb, dbcb, A_log + (size_t)i*DI*DS, Dp + i*DI, yb);
    { dim3 gd(2, 128);
      k_out16h<<<gd, 256, 0, stream>>>(yb, out_wh + (size_t)i*128*128, hbuf); }
  }

  // ---- head (pre-LN fused)
  k_head2<<<8, 256, 0, stream>>>(hbuf, lengths, pre_ln_s, pre_ln_b,
                                 cls_w1, cls_b1, cls_w2, cls_b2, (float*)d_out);
}